// Round 12
// baseline (57.077 us; speedup 1.0000x reference)
//
#include <hip/hip_runtime.h>
#include <hip/hip_bf16.h>
#include <type_traits>

#define AS1 __attribute__((address_space(1)))
#define AS3 __attribute__((address_space(3)))

typedef __attribute__((ext_vector_type(4))) float f32x4;
typedef __attribute__((ext_vector_type(8))) short bf16x8;

static constexpr int B_   = 2048;
static constexpr int IN_  = 1024;
static constexpr int HID_ = 2048;
static constexpr int NB_  = 8;
static constexpr int BS_  = 256;   // block size
static constexpr int G3_  = 768;   // 3*BS_

// ---------- fp32 -> bf16 (RNE) ----------
__device__ __forceinline__ unsigned short f2bf(float f) {
  unsigned u = __builtin_bit_cast(unsigned, f);
  u = (u + 0x7FFFu + ((u >> 16) & 1u)) >> 16;
  return (unsigned short)u;
}

// One launch converts all four fp32 arrays into the contiguous bf16 region in ws.
__global__ void cvt_all(const float* __restrict__ x, const float* __restrict__ h,
                        const float* __restrict__ Wih, const float* __restrict__ Whh,
                        unsigned short* __restrict__ dst) {
  constexpr int c0 = (B_ * IN_) / 4;
  constexpr int c1 = c0 + (B_ * HID_) / 4;
  constexpr int c2 = c1 + (NB_ * G3_ * IN_) / 4;
  constexpr int n4 = c2 + (NB_ * G3_ * BS_) / 4;
  int i = blockIdx.x * blockDim.x + threadIdx.x;
  int stride = gridDim.x * blockDim.x;
  for (; i < n4; i += stride) {
    float4 v;
    if (i < c0)       v = reinterpret_cast<const float4*>(x)[i];
    else if (i < c1)  v = reinterpret_cast<const float4*>(h)[i - c0];
    else if (i < c2)  v = reinterpret_cast<const float4*>(Wih)[i - c1];
    else              v = reinterpret_cast<const float4*>(Whh)[i - c2];
    ushort4 o;
    o.x = f2bf(v.x); o.y = f2bf(v.y); o.z = f2bf(v.z); o.w = f2bf(v.w);
    reinterpret_cast<ushort4*>(dst)[i] = o;
  }
}

// ---------- fused block-GRU MFMA kernel (round-4 skeleton + dep-free frag reads) ----------
// Tile: 128 batch rows x 64 out-cols (192 gate cols); 4 waves (2x2), wave 64x32.
// Accumulators: [0]=r (K=1280 combined), [1]=z (combined), [2]=i_n, [3]=h_n.
// LDS: 2 buffers x { A [128][64]bf16 (16KB) + W [192][64]bf16 (24KB) }, XOR-swizzled
// (phys = logical ^ ((row&7)<<4)); global_load_lds writes linearly so the global
// SOURCE address is pre-swizzled (rule #21).
// Pipeline: stage(0,t0), stage(1,t1); per step: vmcnt(10); barrier; compute;
// lgkmcnt(0); barrier; stage(cur, t+2). FULLY UNROLLED (compile-time indices).
// COMPUTE BODY (the round-12 change): ALL 20 ds_read_b128 go to DISTINCT
// registers (af[2][4], wf[3][2][2] - no WAR reuse across gates), THEN all 48
// MFMAs. Kills the per-gate read->wait->MFMA serialization; compiler staggers
// lgkmcnt so the LDS pipe overlaps the MFMA pipe within the wave.
__global__ __launch_bounds__(256, 2) void gru_mfma(
    const unsigned short* __restrict__ inb,    // [2048][1024] bf16
    const unsigned short* __restrict__ hidb,   // [2048][2048] bf16
    const unsigned short* __restrict__ wihb,   // [8][768][1024] bf16
    const unsigned short* __restrict__ whhb,   // [8][768][256] bf16
    const float* __restrict__ hid_f32,         // [2048][2048] fp32 (h_prev)
    const float* __restrict__ b_ih,            // [8][768]
    const float* __restrict__ b_hh,            // [8][768]
    float* __restrict__ out)                   // [2048][2048]
{
  __shared__ __align__(16) char lds[2][40960];   // per buf: A at 0, W at 16384

  const int t    = threadIdx.x;
  const int lane = t & 63;
  const int wid  = t >> 6;
  const int wm   = wid >> 1;     // wave row (0..1) -> 64-row half
  const int wn   = wid & 1;      // wave col (0..1) -> 32-col half

  // Bijective XCD swizzle: nwg=512 = 8 XCDs x 64 -> each XCD owns one GRU block n.
  const int bid = blockIdx.x;
  const int swz = (bid & 7) * 64 + (bid >> 3);
  const int mt  = swz & 15;
  const int ct  = swz >> 4;
  const int mrow0 = mt * 128;
  const int n     = ct >> 2;          // GRU block index
  const int s0    = (ct & 3) * 64;    // col offset within block

  // Staging pass p writes phys LDS offset op = p*4096 + t*16; the element that
  // belongs there is logical ol = op ^ (((op>>7)&7)<<4) (involution on bits [6:4]).
  int arow[4], acb[4];
#pragma unroll
  for (int p = 0; p < 4; ++p) {
    int op = p * 4096 + t * 16;
    int ol = op ^ (((op >> 7) & 7) << 4);
    arow[p] = ol >> 7; acb[p] = ol & 127;
  }
  int wrowg[6], wsl[6], wcb[6];
#pragma unroll
  for (int p = 0; p < 6; ++p) {
    int op = p * 4096 + t * 16;
    int ol = op ^ (((op >> 7) & 7) << 4);
    int wr = ol >> 7;             // 0..191
    wrowg[p] = wr >> 6;           // gate 0..2
    wsl[p]   = wr & 63;           // col within 64-wide tile
    wcb[p]   = ol & 127;
  }

  f32x4 acc[4][4][2] = {};   // [set][mi][ni]

  // Issue 10 global_load_lds (4 A + 6 W) for K-tile t2 into buffer buf.
  auto stage = [&](int buf, int t2) {
    const bool ph1 = t2 < 16;
    const int ks = ph1 ? t2 : (t2 - 16);
    char* base = (char*)lds[buf];
#pragma unroll
    for (int p = 0; p < 4; ++p) {
      const char* src = ph1
        ? (const char*)inb  + ((size_t)(mrow0 + arow[p]) * IN_  + ks * 64) * 2 + acb[p]
        : (const char*)hidb + ((size_t)(mrow0 + arow[p]) * HID_ + n * BS_ + ks * 64) * 2 + acb[p];
      __builtin_amdgcn_global_load_lds((const AS1 void*)src,
                                       (AS3 void*)(base + p * 4096 + wid * 1024), 16, 0, 0);
    }
#pragma unroll
    for (int p = 0; p < 6; ++p) {
      int grow = n * G3_ + wrowg[p] * BS_ + s0 + wsl[p];
      const char* src = ph1
        ? (const char*)wihb + ((size_t)grow * IN_ + ks * 64) * 2 + wcb[p]
        : (const char*)whhb + ((size_t)grow * BS_ + ks * 64) * 2 + wcb[p];
      __builtin_amdgcn_global_load_lds((const AS1 void*)src,
                                       (AS3 void*)(base + 16384 + p * 4096 + wid * 1024), 16, 0, 0);
    }
  };

  auto compute = [&](int buf, auto ph1c) {
    constexpr bool PH1 = decltype(ph1c)::value;
    const char* Ab = (const char*)lds[buf];
    const char* Wb = (const char*)lds[buf] + 16384;
    bf16x8 af[2][4];       // [ksub][mi]   - 32 VGPR
    bf16x8 wf[3][2][2];    // [g][ksub][ni]- 48 VGPR, NO reuse across gates
    // ---- all 20 ds_read_b128, dependency-free ----
#pragma unroll
    for (int ksub = 0; ksub < 2; ++ksub) {
#pragma unroll
      for (int mi = 0; mi < 4; ++mi) {
        int ar  = wm * 64 + mi * 16 + (lane & 15);
        int off = ar * 128 + ksub * 64 + ((lane >> 4) * 16);
        off ^= (ar & 7) << 4;
        af[ksub][mi] = *reinterpret_cast<const bf16x8*>(Ab + off);
      }
#pragma unroll
      for (int g = 0; g < 3; ++g)
#pragma unroll
        for (int ni = 0; ni < 2; ++ni) {
          int wr  = g * 64 + wn * 32 + ni * 16 + (lane & 15);
          int off = wr * 128 + ksub * 64 + ((lane >> 4) * 16);
          off ^= (wr & 7) << 4;
          wf[g][ksub][ni] = *reinterpret_cast<const bf16x8*>(Wb + off);
        }
    }
    // ---- all 48 MFMAs ----
    __builtin_amdgcn_s_setprio(1);
#pragma unroll
    for (int ksub = 0; ksub < 2; ++ksub)
#pragma unroll
      for (int g = 0; g < 3; ++g) {
        constexpr int set2 = PH1 ? 2 : 3;
        const int set = (g < 2) ? g : set2;
#pragma unroll
        for (int mi = 0; mi < 4; ++mi)
#pragma unroll
          for (int ni = 0; ni < 2; ++ni)
            acc[set][mi][ni] = __builtin_amdgcn_mfma_f32_16x16x32_bf16(
                af[ksub][mi], wf[g][ksub][ni], acc[set][mi][ni], 0, 0, 0);
      }
    __builtin_amdgcn_s_setprio(0);
  };

  // ---- fully-unrolled pipelined K loop: 16 input K-tiles + 4 hidden = 20 ----
  stage(0, 0);
  stage(1, 1);
#pragma unroll
  for (int tt = 0; tt < 20; ++tt) {
    const int cur = tt & 1;   // compile-time under full unroll
    __builtin_amdgcn_sched_barrier(0);
    if (tt < 19) asm volatile("s_waitcnt vmcnt(10)");
    else         asm volatile("s_waitcnt vmcnt(0)");
    __builtin_amdgcn_sched_barrier(0);
    __builtin_amdgcn_s_barrier();          // buf[cur] fully staged for all waves
    if (tt < 16) compute(cur, std::true_type{});
    else         compute(cur, std::false_type{});
    asm volatile("s_waitcnt lgkmcnt(0)");  // my ds_reads from buf[cur] retired
    __builtin_amdgcn_sched_barrier(0);
    __builtin_amdgcn_s_barrier();          // all waves done reading buf[cur]
    if (tt + 2 < 20) stage(cur, tt + 2);   // overwrite now safe
  }

  // ---- epilogue: gates + output ----
#pragma unroll
  for (int ni = 0; ni < 2; ++ni) {
    int scol = s0 + wn * 32 + ni * 16 + (lane & 15);
    float br_i = b_ih[n * G3_ + 0 * BS_ + scol];
    float bz_i = b_ih[n * G3_ + 1 * BS_ + scol];
    float bn_i = b_ih[n * G3_ + 2 * BS_ + scol];
    float br_h = b_hh[n * G3_ + 0 * BS_ + scol];
    float bz_h = b_hh[n * G3_ + 1 * BS_ + scol];
    float bn_h = b_hh[n * G3_ + 2 * BS_ + scol];
    int gcol = n * BS_ + scol;
#pragma unroll
    for (int mi = 0; mi < 4; ++mi) {
#pragma unroll
      for (int i = 0; i < 4; ++i) {
        int row = mrow0 + wm * 64 + mi * 16 + (lane >> 4) * 4 + i;  // C/D: col=lane&15, row=(lane>>4)*4+reg
        float hprev = hid_f32[(size_t)row * HID_ + gcol];
        float rr = acc[0][mi][ni][i] + br_i + br_h;
        float zz = acc[1][mi][ni][i] + bz_i + bz_h;
        float r  = 1.f / (1.f + __expf(-rr));
        float z  = 1.f / (1.f + __expf(-zz));
        float ng = tanhf(acc[2][mi][ni][i] + bn_i + r * (acc[3][mi][ni][i] + bn_h));
        out[(size_t)row * HID_ + gcol] = (1.f - z) * ng + z * hprev;
      }
    }
  }
}

// ---------- fallback (only if ws too small): naive fp32 ----------
__global__ void gru_naive(const float* __restrict__ x, const float* __restrict__ h,
                          const float* __restrict__ Wih, const float* __restrict__ Whh,
                          const float* __restrict__ bih, const float* __restrict__ bhh,
                          float* __restrict__ out) {
  int b = blockIdx.x;
  int n = blockIdx.y;
  int s = threadIdx.x;   // 256
  __shared__ float xs[1024];
  __shared__ float hs[256];
  for (int i = threadIdx.x; i < 1024; i += 256) xs[i] = x[(size_t)b * IN_ + i];
  if (threadIdx.x < 256) hs[threadIdx.x] = h[(size_t)b * HID_ + n * BS_ + threadIdx.x];
  __syncthreads();
  float gi[3], gh[3];
  for (int g = 0; g < 3; ++g) {
    const float* w = Wih + ((size_t)(n * G3_ + g * BS_ + s)) * IN_;
    float a = 0.f;
    for (int k = 0; k < IN_; ++k) a += xs[k] * w[k];
    gi[g] = a + bih[n * G3_ + g * BS_ + s];
    const float* w2 = Whh + ((size_t)(n * G3_ + g * BS_ + s)) * BS_;
    float a2 = 0.f;
    for (int k = 0; k < BS_; ++k) a2 += hs[k] * w2[k];
    gh[g] = a2 + bhh[n * G3_ + g * BS_ + s];
  }
  float r = 1.f / (1.f + expf(-(gi[0] + gh[0])));
  float z = 1.f / (1.f + expf(-(gi[1] + gh[1])));
  float ng = tanhf(gi[2] + r * gh[2]);
  out[(size_t)b * HID_ + n * BS_ + s] = (1.f - z) * ng + z * hs[s];
}

extern "C" void kernel_launch(void* const* d_in, const int* in_sizes, int n_in,
                              void* d_out, int out_size, void* d_ws, size_t ws_size,
                              hipStream_t stream) {
  const float* x   = (const float*)d_in[0];
  const float* h   = (const float*)d_in[1];
  const float* Wih = (const float*)d_in[2];
  const float* Whh = (const float*)d_in[3];
  const float* bih = (const float*)d_in[4];
  const float* bhh = (const float*)d_in[5];
  float* out = (float*)d_out;

  const size_t szin  = (size_t)B_ * IN_;
  const size_t szhid = (size_t)B_ * HID_;
  const size_t szwih = (size_t)NB_ * G3_ * IN_;
  const size_t szwhh = (size_t)NB_ * G3_ * BS_;
  const size_t need  = (szin + szhid + szwih + szwhh) * 2;

  if (ws_size >= need) {
    unsigned short* inb  = (unsigned short*)d_ws;
    unsigned short* hidb = inb + szin;
    unsigned short* wihb = hidb + szhid;
    unsigned short* whhb = wihb + szwih;
    cvt_all<<<2048, 256, 0, stream>>>(x, h, Wih, Whh, (unsigned short*)d_ws);
    gru_mfma<<<512, 256, 0, stream>>>(inb, hidb, wihb, whhb, h, bih, bhh, out);
  } else {
    dim3 grid(B_, NB_);
    gru_naive<<<grid, 256, 0, stream>>>(x, h, Wih, Whh, bih, bhh, out);
  }
}

// Round 13
// 52.621 us; speedup vs baseline: 1.0847x; 1.0847x over previous
//
#include <hip/hip_runtime.h>
#include <hip/hip_bf16.h>
#include <type_traits>

typedef __attribute__((ext_vector_type(4))) float f32x4;
typedef __attribute__((ext_vector_type(8))) short bf16x8;

template <int V> using ic = std::integral_constant<int, V>;

static constexpr int B_   = 2048;
static constexpr int IN_  = 1024;
static constexpr int HID_ = 2048;
static constexpr int NB_  = 8;
static constexpr int BS_  = 256;   // block size
static constexpr int G3_  = 768;   // 3*BS_

// packed fp32x2 -> bf16x2 RNE, single VALU op (no builtin on gfx950)
__device__ __forceinline__ unsigned cvtpk(float lo, float hi) {
  unsigned r;
  asm("v_cvt_pk_bf16_f32 %0, %1, %2" : "=v"(r) : "v"(lo), "v"(hi));
  return r;
}

// ---------- fully-fused block-GRU MFMA kernel, K-step 32 ----------
// Single launch, no workspace: fp32->bf16 conversion rides inside staging.
// Tile: 128 batch rows x 64 out-cols (192 gate cols); 4 waves (2x2), wave 64x32.
// Accumulators: [0]=r (K=1280 combined), [1]=z (combined), [2]=i_n, [3]=h_n.
// LDS: 2 buffers x 20KB { A [128][32]bf16 @0, W [192][32]bf16 @8192 }.
// Rows are 64B; swizzle phys = logical ^ (((byte>>6)&3)<<4): within each 256B
// group (4 rows) slot (r&3, c^(r&3)) -> a wave's 16-row x 4-colgroup b128 read
// covers 1KB with uniform bank spread (minimum pressure, conflict-free).
// Staging (K32 => only 5 passes = 40 VGPR in flight, ONE batch - this is the
// round-13 fix for round-8's spill): issue 10 fp32 loads at step top ->
// compute phase (24 MFMAs + 10 ds_reads) hides latency -> cvt_pk + 5
// ds_write_b128 at tail -> __syncthreads (free drain: loads all consumed).
__global__ __launch_bounds__(256, 2) void gru_mfma(
    const float* __restrict__ xf,     // [2048][1024]
    const float* __restrict__ hf,     // [2048][2048]
    const float* __restrict__ Wih,    // [8][768][1024]
    const float* __restrict__ Whh,    // [8][768][256]
    const float* __restrict__ b_ih,   // [8][768]
    const float* __restrict__ b_hh,   // [8][768]
    float* __restrict__ out)          // [2048][2048]
{
  __shared__ __align__(16) char lds[2][20480];

  const int t    = threadIdx.x;
  const int lane = t & 63;
  const int wid  = t >> 6;
  const int wm   = wid >> 1;     // wave row (0..1) -> 64-row half
  const int wn   = wid & 1;      // wave col (0..1) -> 32-col half

  // Bijective XCD swizzle: nwg=512 = 8 XCDs x 64 -> each XCD owns one GRU block n.
  const int bid = blockIdx.x;
  const int swz = (bid & 7) * 64 + (bid >> 3);
  const int mrow0 = (swz & 15) * 128;
  const int ct    = swz >> 4;
  const int n     = ct >> 2;          // GRU block index
  const int s0    = (ct & 3) * 64;    // col offset within block

  // Staging pass p targets phys offset op = p*4096 + t*16 (region-local);
  // the element that belongs there is logical ol = op ^ (((op>>6)&3)<<4)
  // (involution on byte bits [5:4] keyed by row bits [7:6]).
  int arow[2], acolE[2];
#pragma unroll
  for (int p = 0; p < 2; ++p) {
    int op = p * 4096 + t * 16;
    int ol = op ^ (((op >> 6) & 3) << 4);
    arow[p]  = ol >> 6;           // 0..127
    acolE[p] = (ol & 63) >> 1;    // element offset {0,8,16,24}
  }
  int wgrow[3], wcolE[3];
#pragma unroll
  for (int q = 0; q < 3; ++q) {
    int op = q * 4096 + t * 16;
    int ol = op ^ (((op >> 6) & 3) << 4);
    int wr = ol >> 6;             // 0..191
    wgrow[q]  = n * G3_ + (wr >> 6) * BS_ + s0 + (wr & 63);  // global W row
    wcolE[q]  = (ol & 63) >> 1;
  }

  f32x4 acc[4][4][2] = {};   // [set][mi][ni]
  float4 sa[2][2];           // A staging (16 VGPR)
  float4 sw[3][2];           // W staging (24 VGPR)

  auto issue = [&](int tt) {             // 10 coalesced fp32 loads (40 VGPR)
#pragma unroll
    for (int p = 0; p < 2; ++p) {
      const float* src = (tt < 32)
        ? xf + (size_t)(mrow0 + arow[p]) * IN_  + tt * 32 + acolE[p]
        : hf + (size_t)(mrow0 + arow[p]) * HID_ + n * BS_ + (tt - 32) * 32 + acolE[p];
      sa[p][0] = *reinterpret_cast<const float4*>(src);
      sa[p][1] = *reinterpret_cast<const float4*>(src + 4);
    }
#pragma unroll
    for (int q = 0; q < 3; ++q) {
      const float* src = (tt < 32)
        ? Wih + (size_t)wgrow[q] * IN_ + tt * 32 + wcolE[q]
        : Whh + (size_t)wgrow[q] * BS_ + (tt - 32) * 32 + wcolE[q];
      sw[q][0] = *reinterpret_cast<const float4*>(src);
      sw[q][1] = *reinterpret_cast<const float4*>(src + 4);
    }
  };
  auto pack8 = [&](const float4& a, const float4& b) {
    union { unsigned u[4]; bf16x8 v; } r;
    r.u[0] = cvtpk(a.x, a.y); r.u[1] = cvtpk(a.z, a.w);
    r.u[2] = cvtpk(b.x, b.y); r.u[3] = cvtpk(b.z, b.w);
    return r.v;
  };
  auto writeAll = [&](int buf) {         // cvt + 5 ds_write_b128 (linear phys)
    char* base = (char*)lds[buf];
#pragma unroll
    for (int p = 0; p < 2; ++p)
      *reinterpret_cast<bf16x8*>(base + p * 4096 + t * 16) = pack8(sa[p][0], sa[p][1]);
#pragma unroll
    for (int q = 0; q < 3; ++q)
      *reinterpret_cast<bf16x8*>(base + 8192 + q * 4096 + t * 16) = pack8(sw[q][0], sw[q][1]);
  };

  auto compute = [&](int buf, auto ph1c) {
    constexpr bool PH1 = decltype(ph1c)::value;
    const char* base = (const char*)lds[buf];
    bf16x8 af[4];
#pragma unroll
    for (int mi = 0; mi < 4; ++mi) {
      int ar  = wm * 64 + mi * 16 + (lane & 15);
      int off = (ar * 64 + ((lane >> 4) * 16)) ^ ((ar & 3) << 4);
      af[mi] = *reinterpret_cast<const bf16x8*>(base + off);
    }
    __builtin_amdgcn_s_setprio(1);
#pragma unroll
    for (int g = 0; g < 3; ++g) {
      bf16x8 wf[2];
#pragma unroll
      for (int ni = 0; ni < 2; ++ni) {
        int wr  = g * 64 + wn * 32 + ni * 16 + (lane & 15);
        int off = (wr * 64 + ((lane >> 4) * 16)) ^ ((wr & 3) << 4);
        wf[ni] = *reinterpret_cast<const bf16x8*>(base + 8192 + off);
      }
      constexpr int set2 = PH1 ? 2 : 3;
      const int set = (g < 2) ? g : set2;
#pragma unroll
      for (int mi = 0; mi < 4; ++mi)
#pragma unroll
        for (int ni = 0; ni < 2; ++ni)
          acc[set][mi][ni] = __builtin_amdgcn_mfma_f32_16x16x32_bf16(
              af[mi], wf[ni], acc[set][mi][ni], 0, 0, 0);
    }
    __builtin_amdgcn_s_setprio(0);
  };

  // ---- prologue: stage tile 0 into buf0 ----
  issue(0);
  writeAll(0);
  __syncthreads();

  // ---- 40 K-steps (32 input + 8 hidden), fully unrolled, ONE barrier each ----
#pragma unroll
  for (int tt = 0; tt < 40; ++tt) {
    const int cur = tt & 1;

    if (tt < 39) issue(tt + 1);             // T14: issue early
    __builtin_amdgcn_sched_barrier(0);      // loads stay above compute
    if (tt < 32) compute(cur, std::true_type{});
    else         compute(cur, std::false_type{});
    __builtin_amdgcn_sched_barrier(0);      // write-late boundary
    if (tt < 39) writeAll(cur ^ 1);
    __syncthreads();   // writes visible; reads of cur retired; loads consumed
  }

  // ---- epilogue: gates + output ----
#pragma unroll
  for (int ni = 0; ni < 2; ++ni) {
    int scol = s0 + wn * 32 + ni * 16 + (lane & 15);
    float br_i = b_ih[n * G3_ + 0 * BS_ + scol];
    float bz_i = b_ih[n * G3_ + 1 * BS_ + scol];
    float bn_i = b_ih[n * G3_ + 2 * BS_ + scol];
    float br_h = b_hh[n * G3_ + 0 * BS_ + scol];
    float bz_h = b_hh[n * G3_ + 1 * BS_ + scol];
    float bn_h = b_hh[n * G3_ + 2 * BS_ + scol];
    int gcol = n * BS_ + scol;
#pragma unroll
    for (int mi = 0; mi < 4; ++mi) {
#pragma unroll
      for (int i = 0; i < 4; ++i) {
        int row = mrow0 + wm * 64 + mi * 16 + (lane >> 4) * 4 + i;  // C/D: col=lane&15, row=(lane>>4)*4+reg
        float hprev = hf[(size_t)row * HID_ + gcol];
        float rr = acc[0][mi][ni][i] + br_i + br_h;
        float zz = acc[1][mi][ni][i] + bz_i + bz_h;
        float r  = 1.f / (1.f + __expf(-rr));
        float z  = 1.f / (1.f + __expf(-zz));
        float ng = tanhf(acc[2][mi][ni][i] + bn_i + r * (acc[3][mi][ni][i] + bn_h));
        out[(size_t)row * HID_ + gcol] = (1.f - z) * ng + z * hprev;
      }
    }
  }
}

extern "C" void kernel_launch(void* const* d_in, const int* in_sizes, int n_in,
                              void* d_out, int out_size, void* d_ws, size_t ws_size,
                              hipStream_t stream) {
  const float* x   = (const float*)d_in[0];
  const float* h   = (const float*)d_in[1];
  const float* Wih = (const float*)d_in[2];
  const float* Whh = (const float*)d_in[3];
  const float* bih = (const float*)d_in[4];
  const float* bhh = (const float*)d_in[5];
  float* out = (float*)d_out;
  (void)d_ws; (void)ws_size;

  gru_mfma<<<512, 256, 0, stream>>>(x, h, Wih, Whh, bih, bhh, out);
}